// Round 1
// 1092.318 us; speedup vs baseline: 1.4761x; 1.4761x over previous
//
#include <hip/hip_runtime.h>

typedef unsigned int u32;
typedef unsigned short u16;

#define THREADS 256

__device__ __forceinline__ float blo(u32 u){ return __uint_as_float(u << 16); }
__device__ __forceinline__ float bhi(u32 u){ return __uint_as_float(u & 0xffff0000u); }
__device__ __forceinline__ u16 f2bf(float f){
  u32 u = __float_as_uint(f);
  u += 0x7fffu + ((u >> 16) & 1u);
  return (u16)(u >> 16);
}
__device__ __forceinline__ u32 pack2(float a, float b){
  return (u32)f2bf(a) | ((u32)f2bf(b) << 16);
}

// sWb layout (u32 units, bf16-pair packed):
//   phase A: gw1 [0,4096), gb1 [4096,4128)
//   phase B: gw2 [0,4608), gb2 [4608,4680), WU0 [4680,5704), WV0 [5704,6728),
//            WU1 [6728,7240), WV1 [7240,7752), WU2 [7752,8008), WV2 [8008,8264)
#define OFF_GB2 4608
#define OFF_U0  4680
#define OFF_V0  5704
#define OFF_U1  6728
#define OFF_V1  7240
#define OFF_U2  7752
#define OFF_V2  8008
#define SWB_SZ  8264

#define RED_WIN 64

__global__ __launch_bounds__(THREADS, 2) void fused_kernel(
    const int* __restrict__ batch,
    const float* __restrict__ xs, const float* __restrict__ xsph,
    const float2* __restrict__ WU0, const float2* __restrict__ WU1, const float2* __restrict__ WU2,
    const float2* __restrict__ WV0, const float2* __restrict__ WV1, const float2* __restrict__ WV2,
    const float2* __restrict__ gw1, const float2* __restrict__ gb1,
    const float2* __restrict__ gw2, const float2* __restrict__ gb2,
    const float* __restrict__ Wp0, const float* __restrict__ Wp1, const float* __restrict__ Wp2,
    float* __restrict__ accum, int NA)
{
  __shared__ u32  sWb[SWB_SZ];        // 33056 B: staged weights (bf16 pairs)
  __shared__ u32  sWh[16*512];        // 32768 B: h per thread, [pair p][tid][2] u32
  __shared__ float red[RED_WIN*9];    // 2304 B: per-block graph reduction window
  const int tid  = threadIdx.x;
  const int atom = blockIdx.x * THREADS + tid;
  const bool act = atom < NA;

  for (int i = tid; i < RED_WIN*9; i += THREADS) red[i] = 0.f;
  int lastIdx = blockIdx.x * THREADS + (THREADS - 1);
  if (lastIdx > NA - 1) lastIdx = NA - 1;
  const int gmin = batch[blockIdx.x * THREADS];
  const int gmax = batch[lastIdx];

  // ---------------- phase A staging: fp32 -> packed bf16 pairs ----------------
  for (int i = tid; i < 4128; i += THREADS){
    float2 v = (i < 4096) ? gw1[i] : gb1[i - 4096];
    sWb[i] = pack2(v.x, v.y);
  }
  __syncthreads();

  // ---------------- phase A: h = silu(xs @ gw1 + gb1), store bf16 to LDS -----
  if (act){
    float h[64];
#pragma unroll
    for (int c = 0; c < 64; ++c) h[c] = 0.f;
    const float4* xr = (const float4*)(xs + (size_t)atom * 128);
    float4 xv = xr[0];
#pragma unroll 1
    for (int k4 = 0; k4 < 32; ++k4){
      float4 xn = xr[(k4 + 1) & 31];          // prefetch next (wraps harmlessly)
      const u32* w0 = &sWb[(4*k4) * 32];
#pragma unroll
      for (int c = 0; c < 32; ++c){
        u32 a = w0[c], b = w0[32+c], cc = w0[64+c], d = w0[96+c];
        h[2*c]   += xv.x*blo(a) + xv.y*blo(b) + xv.z*blo(cc) + xv.w*blo(d);
        h[2*c+1] += xv.x*bhi(a) + xv.y*bhi(b) + xv.z*bhi(cc) + xv.w*bhi(d);
      }
      xv = xn;
    }
#pragma unroll
    for (int cp = 0; cp < 16; ++cp){
      u32 b0 = sWb[4096 + 2*cp], b1 = sWb[4096 + 2*cp + 1];
      float z0 = h[4*cp]   + blo(b0);
      float z1 = h[4*cp+1] + bhi(b0);
      float z2 = h[4*cp+2] + blo(b1);
      float z3 = h[4*cp+3] + bhi(b1);
      z0 = z0 / (1.f + __expf(-z0));
      z1 = z1 / (1.f + __expf(-z1));
      z2 = z2 / (1.f + __expf(-z2));
      z3 = z3 / (1.f + __expf(-z3));
      uint2 hv; hv.x = pack2(z0, z1); hv.y = pack2(z2, z3);
      *(uint2*)&sWh[cp*512 + tid*2] = hv;     // conflict-free: lane-linear 8B
    }
  }
  __syncthreads();

  // ---------------- phase B staging ----------------
  for (int i = tid; i < SWB_SZ; i += THREADS){
    float2 v;
    if      (i < OFF_GB2) v = gw2[i];
    else if (i < OFF_U0)  v = gb2[i - OFF_GB2];
    else if (i < OFF_V0)  v = WU0[i - OFF_U0];
    else if (i < OFF_U1)  v = WV0[i - OFF_V0];
    else if (i < OFF_V1)  v = WU1[i - OFF_U1];
    else if (i < OFF_U2)  v = WV1[i - OFF_V1];
    else if (i < OFF_V2)  v = WU2[i - OFF_U2];
    else                  v = WV2[i - OFF_V2];
    sWb[i] = pack2(v.x, v.y);
  }
  __syncthreads();

  if (act){
    const float4* row4 = (const float4*)(xsph + (size_t)atom * 480);
    float o0 = 0.f, o2 = 0.f, o6 = 0.f;
    float o1[5] = {0,0,0,0,0}, o4[5] = {0,0,0,0,0}, o5[5] = {0,0,0,0,0}, o8[5] = {0,0,0,0,0};
    float o3[3] = {0,0,0}, o7[3] = {0,0,0};

    for (int half = 0; half < 2; ++half){
      const int co = half * 4;   // u32 column offset into 8-u32 (16-ch) weight rows

      // w-slice for instruction k (8 channels of this half); h read back from LDS
      auto calcw = [&](int k, float* wsl){
#pragma unroll
        for (int c = 0; c < 4; ++c){
          u32 b = sWb[OFF_GB2 + k*8 + co + c];
          wsl[2*c] = blo(b); wsl[2*c+1] = bhi(b);
        }
        const u32* wrow = &sWb[k*8 + co];
#pragma unroll 1
        for (int p = 0; p < 16; ++p){          // 4 gw2 rows per iteration
          uint2 hh = *(const uint2*)&sWh[p*512 + tid*2];
          float h0 = blo(hh.x), h1 = bhi(hh.x), h2 = blo(hh.y), h3 = bhi(hh.y);
          const u32* r0 = wrow + p*288;        // rows 4p..4p+3, stride 72 u32
#pragma unroll
          for (int c = 0; c < 4; ++c){
            u32 a = r0[c], b = r0[72+c], d = r0[144+c], e = r0[216+c];
            wsl[2*c]   += h0*blo(a) + h1*blo(b) + h2*blo(d) + h3*blo(e);
            wsl[2*c+1] += h0*bhi(a) + h1*bhi(b) + h2*bhi(d) + h3*bhi(e);
          }
        }
      };

      float wsl[8];

      // ---- l = 0 : U0, V0 (8 channels of this half) ----
      float aU0[8], aV0[8];
#pragma unroll
      for (int c = 0; c < 8; ++c){ aU0[c] = 0.f; aV0[c] = 0.f; }
      {
        float4 xv = row4[0];
#pragma unroll 1
        for (int k4 = 0; k4 < 32; ++k4){
          float4 xn = row4[(k4 + 1) & 31];
          float xe[4] = {xv.x, xv.y, xv.z, xv.w};
#pragma unroll
          for (int e = 0; e < 4; ++e){
            const u32* wu = &sWb[OFF_U0 + (4*k4 + e)*8 + co];
            const u32* wv = &sWb[OFF_V0 + (4*k4 + e)*8 + co];
            float x = xe[e];
#pragma unroll
            for (int c = 0; c < 4; ++c){
              u32 a = wu[c], b = wv[c];
              aU0[2*c]   += x*blo(a);
              aU0[2*c+1] += x*bhi(a);
              aV0[2*c]   += x*blo(b);
              aV0[2*c+1] += x*bhi(b);
            }
          }
          xv = xn;
        }
      }
#pragma unroll
      for (int c = 0; c < 8; ++c){ aU0[c] *= 0.08838834764831845f; aV0[c] *= 0.08838834764831845f; }

      calcw(0, wsl);                               // k0 (0,0,0)
#pragma unroll
      for (int u = 0; u < 8; ++u) o0 += aU0[u]*aV0[u]*wsl[u];

      // ---- l = 1 : U1, V1 (3 comps x 8 channels) ----
      {
        float aU1[24], aV1[24];
#pragma unroll
        for (int c = 0; c < 24; ++c){ aU1[c] = 0.f; aV1[c] = 0.f; }
        float4 fa = row4[32], fb = row4[33], fc = row4[34];
#pragma unroll 1
        for (int g4 = 0; g4 < 16; ++g4){
          int gn = (g4 + 1) & 15;
          float4 na = row4[32 + 3*gn], nb = row4[33 + 3*gn], nc = row4[34 + 3*gn];
          float f12[12] = {fa.x,fa.y,fa.z,fa.w, fb.x,fb.y,fb.z,fb.w, fc.x,fc.y,fc.z,fc.w};
#pragma unroll
          for (int s = 0; s < 4; ++s){
            int uu = 4*g4 + s;
            float x0 = f12[3*s], x1 = f12[3*s+1], x2 = f12[3*s+2];
            const u32* wu = &sWb[OFF_U1 + uu*8 + co];
            const u32* wv = &sWb[OFF_V1 + uu*8 + co];
#pragma unroll
            for (int c = 0; c < 4; ++c){
              u32 a = wu[c];
              float uA = blo(a), uAh = bhi(a);
              aU1[2*c]      += x0*uA;  aU1[2*c+1]    += x0*uAh;
              aU1[8+2*c]    += x1*uA;  aU1[8+2*c+1]  += x1*uAh;
              aU1[16+2*c]   += x2*uA;  aU1[16+2*c+1] += x2*uAh;
              u32 b = wv[c];
              float vA = blo(b), vAh = bhi(b);
              aV1[2*c]      += x0*vA;  aV1[2*c+1]    += x0*vAh;
              aV1[8+2*c]    += x1*vA;  aV1[8+2*c+1]  += x1*vAh;
              aV1[16+2*c]   += x2*vA;  aV1[16+2*c+1] += x2*vAh;
            }
          }
          fa = na; fb = nb; fc = nc;
        }
#pragma unroll
        for (int c = 0; c < 24; ++c){ aU1[c] *= 0.125f; aV1[c] *= 0.125f; }

        calcw(2, wsl);                             // k2 (1,1,0)
#pragma unroll
        for (int u = 0; u < 8; ++u)
          o2 += (aU1[u]*aV1[u] + aU1[8+u]*aV1[8+u] + aU1[16+u]*aV1[16+u]) * wsl[u];

        calcw(3, wsl);                             // k3 (1,1,1)
#pragma unroll
        for (int u = 0; u < 8; ++u){
          float a0 = aU1[u], a1 = aU1[8+u], a2 = aU1[16+u];
          float b0 = aV1[u], b1 = aV1[8+u], b2 = aV1[16+u];
          float wv = wsl[u];
          o3[0] += wv*(a1*b2 - a2*b1);
          o3[1] += wv*(a2*b0 - a0*b2);
          o3[2] += wv*(a0*b1 - a1*b0);
        }

        calcw(4, wsl);                             // k4 (1,1,2)
#pragma unroll
        for (int u = 0; u < 8; ++u){
          float wv = wsl[u];
          float a0 = aU1[u]*wv, a1 = aU1[8+u]*wv, a2 = aU1[16+u]*wv;
          float b0 = aV1[u], b1 = aV1[8+u], b2 = aV1[16+u];
          o4[0] += -0.17677669529663687f*(a0*b2 + a2*b0);
          o4[1] += -0.17677669529663687f*(a0*b1 + a1*b0);
          o4[2] +=  0.10206207261596577f*(a0*b0 + a2*b2) - 0.20412414523193154f*a1*b1;
          o4[3] += -0.17677669529663687f*(a2*b1 + a1*b2);
          o4[4] +=  0.17677669529663687f*(a0*b0 - a2*b2);
        }
      }

      // ---- l = 2 : U2, V2 (5 comps x 8 channels) ----
      {
        float aU2[40], aV2[40];
#pragma unroll
        for (int c = 0; c < 40; ++c){ aU2[c] = 0.f; aV2[c] = 0.f; }
        float4 qa = row4[80], qb = row4[81], qc = row4[82], qd = row4[83], qe = row4[84];
#pragma unroll 1
        for (int g4 = 0; g4 < 8; ++g4){
          int gn = (g4 + 1) & 7;
          float4 pa = row4[80+5*gn], pb = row4[81+5*gn], pc = row4[82+5*gn],
                 pd = row4[83+5*gn], pe = row4[84+5*gn];
          float f20[20] = {qa.x,qa.y,qa.z,qa.w, qb.x,qb.y,qb.z,qb.w, qc.x,qc.y,qc.z,qc.w,
                           qd.x,qd.y,qd.z,qd.w, qe.x,qe.y,qe.z,qe.w};
#pragma unroll
          for (int s = 0; s < 4; ++s){
            int uu = 4*g4 + s;
            const u32* wu = &sWb[OFF_U2 + uu*8 + co];
            const u32* wv = &sWb[OFF_V2 + uu*8 + co];
#pragma unroll
            for (int c = 0; c < 4; ++c){
              u32 a = wu[c];
              float uA = blo(a), uAh = bhi(a);
              u32 b = wv[c];
              float vA = blo(b), vAh = bhi(b);
#pragma unroll
              for (int m = 0; m < 5; ++m){
                float xm = f20[5*s + m];
                aU2[m*8+2*c]   += xm*uA;
                aU2[m*8+2*c+1] += xm*uAh;
                aV2[m*8+2*c]   += xm*vA;
                aV2[m*8+2*c+1] += xm*vAh;
              }
            }
          }
          qa=pa; qb=pb; qc=pc; qd=pd; qe=pe;
        }
#pragma unroll
        for (int c = 0; c < 40; ++c){ aU2[c] *= 0.17677669529663687f; aV2[c] *= 0.17677669529663687f; }

        calcw(1, wsl);                             // k1 (0,2,2)
#pragma unroll
        for (int u = 0; u < 8; ++u){
          float t = aU0[u]*wsl[u];
          o1[0] += t*aV2[u];      o1[1] += t*aV2[8+u];  o1[2] += t*aV2[16+u];
          o1[3] += t*aV2[24+u];   o1[4] += t*aV2[32+u];
        }

        calcw(5, wsl);                             // k5 (2,0,2)
#pragma unroll
        for (int u = 0; u < 8; ++u){
          float t = aV0[u]*wsl[u];
          o5[0] += aU2[u]*t;      o5[1] += aU2[8+u]*t;  o5[2] += aU2[16+u]*t;
          o5[3] += aU2[24+u]*t;   o5[4] += aU2[32+u]*t;
        }

        calcw(6, wsl);                             // k6 (2,2,0)
#pragma unroll
        for (int u = 0; u < 8; ++u)
          o6 += wsl[u]*(aU2[u]*aV2[u] + aU2[8+u]*aV2[8+u] + aU2[16+u]*aV2[16+u]
                      + aU2[24+u]*aV2[24+u] + aU2[32+u]*aV2[32+u]);

        calcw(7, wsl);                             // k7 (2,2,1)
#pragma unroll
        for (int u = 0; u < 8; ++u){
          float wv = wsl[u];
          float A0 = aU2[u], A1 = aU2[8+u], A2 = aU2[16+u], A3 = aU2[24+u], A4 = aU2[32+u];
          float B0 = aV2[u], B1 = aV2[8+u], B2 = aV2[16+u], B3 = aV2[24+u], B4 = aV2[32+u];
          o7[0] += wv*( 0.07905694150420949f*(A0*B1 - A1*B0)
                       -0.13693063937629153f*(A2*B3 - A3*B2)
                       -0.07905694150420949f*(A3*B4 - A4*B3));
          o7[1] += wv*( 0.15811388300841897f*(A0*B4 - A4*B0)
                       +0.07905694150420949f*(A1*B3 - A3*B1));
          o7[2] += wv*(-0.07905694150420949f*(A0*B3 - A3*B0)
                       -0.13693063937629153f*(A1*B2 - A2*B1)
                       -0.07905694150420949f*(A1*B4 - A4*B1));
        }

        calcw(8, wsl);                             // k8 (2,2,2)
#pragma unroll
        for (int u = 0; u < 8; ++u){
          float wv = wsl[u];
          float A0 = aU2[u]*wv, A1 = aU2[8+u]*wv, A2 = aU2[16+u]*wv, A3 = aU2[24+u]*wv, A4 = aU2[32+u]*wv;
          float B0 = aV2[u], B1 = aV2[8+u], B2 = aV2[16+u], B3 = aV2[24+u], B4 = aV2[32+u];
          o8[0] +=  0.13363062095621219f*(A0*B2 + A2*B0) - 0.11572751768169277f*(A1*B3 + A3*B1);
          o8[1] += -0.06681531047810609f*(A1*B2 + A2*B1) + 0.11572751768169277f*(A1*B4 + A4*B1)
                   -0.11572751768169277f*(A0*B3 + A3*B0);
          o8[2] +=  0.13363062095621219f*(A0*B0 + A4*B4) - 0.06681531047810609f*(A1*B1 + A3*B3)
                   -0.13363062095621219f*A2*B2;
          o8[3] += -0.11572751768169277f*(A0*B1 + A1*B0) - 0.06681531047810609f*(A2*B3 + A3*B2)
                   -0.11572751768169277f*(A3*B4 + A4*B3);
          o8[4] +=  0.13363062095621219f*(A2*B4 + A4*B2) + 0.11572751768169277f*(A1*B1 - A3*B3);
        }
      }
    } // half

    o0 *= 0.25f;
    o2 *= 0.14433756729740643f;
    o6 *= 0.11180339887498948f;

    float p00 = Wp0[0], p01 = Wp0[1], p02 = Wp0[2];
    float p10 = Wp1[0], p11 = Wp1[1];
    float p20 = Wp2[0], p21 = Wp2[1], p22 = Wp2[2], p23 = Wp2[3];
    float ao[9];
    ao[0] = (o0*p00 + o2*p01 + o6*p02) * 0.5773502691896258f;
#pragma unroll
    for (int i = 0; i < 3; ++i)
      ao[1+i] = (o3[i]*0.17677669529663687f*p10 + o7[i]*p11) * 0.7071067811865476f;
#pragma unroll
    for (int m = 0; m < 5; ++m)
      ao[4+m] = (o1[m]*0.25f*p20 + o4[m]*p21 + o5[m]*0.25f*p22 + o8[m]*p23) * 0.5f;

    int g = batch[atom];
    int off = g - gmin;
    if (off >= 0 && off < RED_WIN){
#pragma unroll
      for (int c = 0; c < 9; ++c) atomicAdd(&red[off*9 + c], ao[c]);
    } else {
#pragma unroll
      for (int c = 0; c < 9; ++c) atomicAdd(&accum[g*9 + c], ao[c]);
    }
  }
  __syncthreads();

  int range = gmax - gmin + 1; if (range > RED_WIN) range = RED_WIN;
  for (int i = tid; i < range*9; i += THREADS){
    float v = red[i];
    if (v != 0.f) atomicAdd(&accum[(gmin + i/9)*9 + (i%9)], v);
  }
}

// ---------------- final: res_sph @ Q, permute, write fp32 ----------------
__constant__ float Qc[81] = {
  0.5773502691896258f, 0.f, 0.f,  0.f, 0.5773502691896258f, 0.f,  0.f, 0.f, 0.5773502691896258f,
  0.f, 0.f, 0.f,  0.f, 0.f, 0.7071067811865476f,  0.f, -0.7071067811865476f, 0.f,
  0.f, 0.f, -0.7071067811865476f,  0.f, 0.f, 0.f,  0.7071067811865476f, 0.f, 0.f,
  0.f, 0.7071067811865476f, 0.f,  -0.7071067811865476f, 0.f, 0.f,  0.f, 0.f, 0.f,
  0.f, 0.f, -0.7071067811865476f,  0.f, 0.f, 0.f,  -0.7071067811865476f, 0.f, 0.f,
  0.f, -0.7071067811865476f, 0.f,  -0.7071067811865476f, 0.f, 0.f,  0.f, 0.f, 0.f,
  0.4082482904638631f, 0.f, 0.f,  0.f, -0.8164965809277260f, 0.f,  0.f, 0.f, 0.4082482904638631f,
  0.f, 0.f, 0.f,  0.f, 0.f, -0.7071067811865476f,  0.f, -0.7071067811865476f, 0.f,
  0.7071067811865476f, 0.f, 0.f,  0.f, 0.f, 0.f,  0.f, 0.f, -0.7071067811865476f
};

__global__ __launch_bounds__(THREADS) void final_kernel(
    const float* __restrict__ accum, float* __restrict__ out, int NG)
{
  int t = blockIdx.x * THREADS + threadIdx.x;
  if (t >= NG*9) return;
  int g = t / 9, r = t - 9*g, i = r / 3, j = r - 3*i;
  int a = (i == 0) ? 2 : (i == 1 ? 0 : 1);
  int b = (j == 0) ? 2 : (j == 1 ? 0 : 1);
  float s = 0.f;
#pragma unroll
  for (int rr = 0; rr < 9; ++rr) s += accum[g*9 + rr] * Qc[rr*9 + a*3 + b];
  out[t] = s;
}

// ---------------- launch ----------------
extern "C" void kernel_launch(void* const* d_in, const int* in_sizes, int n_in,
                              void* d_out, int out_size, void* d_ws, size_t ws_size,
                              hipStream_t stream)
{
  (void)n_in; (void)ws_size;
  const int NA = in_sizes[0];
  const int NG = out_size / 9;

  const int*    batch = (const int*)d_in[0];
  const float*  xs    = (const float*)d_in[1];
  const float*  xsph  = (const float*)d_in[2];
  const float2* WU0   = (const float2*)d_in[3];
  const float2* WU1   = (const float2*)d_in[4];
  const float2* WU2   = (const float2*)d_in[5];
  const float2* WV0   = (const float2*)d_in[6];
  const float2* WV1   = (const float2*)d_in[7];
  const float2* WV2   = (const float2*)d_in[8];
  const float2* gw1   = (const float2*)d_in[9];
  const float2* gb1   = (const float2*)d_in[10];
  const float2* gw2   = (const float2*)d_in[11];
  const float2* gb2   = (const float2*)d_in[12];
  const float*  Wp0   = (const float*)d_in[13];
  const float*  Wp1   = (const float*)d_in[14];
  const float*  Wp2   = (const float*)d_in[15];

  float* accum = (float*)d_ws;   // NG*9 fp32 = 36 KB

  int nb = (NA + THREADS - 1) / THREADS;
  hipMemsetAsync(accum, 0, (size_t)NG * 9 * sizeof(float), stream);
  fused_kernel<<<dim3(nb), dim3(THREADS), 0, stream>>>(
      batch, xs, xsph, WU0, WU1, WU2, WV0, WV1, WV2,
      gw1, gb1, gw2, gb2, Wp0, Wp1, Wp2, accum, NA);
  final_kernel<<<dim3((NG*9 + THREADS - 1)/THREADS), dim3(THREADS), 0, stream>>>(
      accum, (float*)d_out, NG);
}

// Round 2
// 1082.407 us; speedup vs baseline: 1.4897x; 1.0092x over previous
//
#include <hip/hip_runtime.h>

typedef unsigned int u32;
typedef unsigned short u16;

#define THREADS 256

__device__ __forceinline__ float blo(u32 u){ return __uint_as_float(u << 16); }
__device__ __forceinline__ float bhi(u32 u){ return __uint_as_float(u & 0xffff0000u); }
__device__ __forceinline__ u16 f2bf(float f){
  u32 u = __float_as_uint(f);
  u += 0x7fffu + ((u >> 16) & 1u);
  return (u16)(u >> 16);
}
__device__ __forceinline__ u32 pack2(float a, float b){
  return (u32)f2bf(a) | ((u32)f2bf(b) << 16);
}

// one v_dot2_f32_bf16: acc += lo(a)*lo(b) + hi(a)*hi(b), all bf16 inputs
__device__ __forceinline__ void dot2bf(float& acc, u32 a, u32 b){
  asm("v_dot2_f32_bf16 %0, %1, %2, %0" : "+v"(acc) : "v"(a), "v"(b));
}

// sWb layout (u32 units, bf16-pair packed):
//   phase A: gw1 [0,4096), gb1 [4096,4128)
//   phase B: gw2 J-PAIRED [0,4608): index jp*144+ch, u32 = (gw2[2jp][ch], gw2[2jp+1][ch])
//            gb2 [4608,4680) (channel pairs), WU0 [4680,5704), WV0 [5704,6728),
//            WU1 [6728,7240), WV1 [7240,7752), WU2 [7752,8008), WV2 [8008,8264)
#define OFF_GB2 4608
#define OFF_U0  4680
#define OFF_V0  5704
#define OFF_U1  6728
#define OFF_V1  7240
#define OFF_U2  7752
#define OFF_V2  8008
#define SWB_SZ  8264

#define RED_WIN 64

__global__ __launch_bounds__(THREADS)
__attribute__((amdgpu_waves_per_eu(2, 2)))
void fused_kernel(
    const int* __restrict__ batch,
    const float* __restrict__ xs, const float* __restrict__ xsph,
    const float2* __restrict__ WU0, const float2* __restrict__ WU1, const float2* __restrict__ WU2,
    const float2* __restrict__ WV0, const float2* __restrict__ WV1, const float2* __restrict__ WV2,
    const float2* __restrict__ gw1, const float2* __restrict__ gb1,
    const float2* __restrict__ gw2, const float2* __restrict__ gb2,
    const float* __restrict__ Wp0, const float* __restrict__ Wp1, const float* __restrict__ Wp2,
    float* __restrict__ accum, int NA)
{
  __shared__ u32  sWb[SWB_SZ];        // 33056 B: staged weights (bf16 pairs)
  __shared__ u32  sWh[16*512];        // 32768 B: h per thread, [pair p][tid][2] u32
  __shared__ float red[RED_WIN*9];    // 2304 B: per-block graph reduction window
  const int tid  = threadIdx.x;
  const int atom = blockIdx.x * THREADS + tid;
  const bool act = atom < NA;

  for (int i = tid; i < RED_WIN*9; i += THREADS) red[i] = 0.f;
  int lastIdx = blockIdx.x * THREADS + (THREADS - 1);
  if (lastIdx > NA - 1) lastIdx = NA - 1;
  const int gmin = batch[blockIdx.x * THREADS];
  const int gmax = batch[lastIdx];

  // ---------------- phase A staging: fp32 -> packed bf16 pairs ----------------
  for (int i = tid; i < 4128; i += THREADS){
    float2 v = (i < 4096) ? gw1[i] : gb1[i - 4096];
    sWb[i] = pack2(v.x, v.y);
  }
  __syncthreads();

  // ---------------- phase A: h = silu(xs @ gw1 + gb1), store bf16 to LDS -----
  if (act){
    float h[64];
#pragma unroll
    for (int c = 0; c < 64; ++c) h[c] = 0.f;
    const float4* xr = (const float4*)(xs + (size_t)atom * 128);
    float4 xv = xr[0];
#pragma unroll 1
    for (int k4 = 0; k4 < 32; ++k4){
      float4 xn = xr[(k4 + 1) & 31];          // prefetch next (wraps harmlessly)
      const u32* w0 = &sWb[(4*k4) * 32];
#pragma unroll
      for (int c = 0; c < 32; ++c){
        u32 a = w0[c], b = w0[32+c], cc = w0[64+c], d = w0[96+c];
        h[2*c]   += xv.x*blo(a) + xv.y*blo(b) + xv.z*blo(cc) + xv.w*blo(d);
        h[2*c+1] += xv.x*bhi(a) + xv.y*bhi(b) + xv.z*bhi(cc) + xv.w*bhi(d);
      }
      xv = xn;
    }
#pragma unroll
    for (int cp = 0; cp < 16; ++cp){
      u32 b0 = sWb[4096 + 2*cp], b1 = sWb[4096 + 2*cp + 1];
      float z0 = h[4*cp]   + blo(b0);
      float z1 = h[4*cp+1] + bhi(b0);
      float z2 = h[4*cp+2] + blo(b1);
      float z3 = h[4*cp+3] + bhi(b1);
      z0 = z0 / (1.f + __expf(-z0));
      z1 = z1 / (1.f + __expf(-z1));
      z2 = z2 / (1.f + __expf(-z2));
      z3 = z3 / (1.f + __expf(-z3));
      uint2 hv; hv.x = pack2(z0, z1); hv.y = pack2(z2, z3);
      *(uint2*)&sWh[cp*512 + tid*2] = hv;     // conflict-free: lane-linear 8B
    }
  }
  __syncthreads();

  // ---------------- phase B staging ----------------
  {
    const float* gw2f = (const float*)gw2;
    for (int i = tid; i < SWB_SZ; i += THREADS){
      float2 v;
      if (i < OFF_GB2){
        // j-paired repack: u32 i = (jp, ch) -> (gw2[2jp][ch], gw2[2jp+1][ch])
        int jp = i / 144, ch = i - jp*144;
        v.x = gw2f[(2*jp)*144 + ch];
        v.y = gw2f[(2*jp+1)*144 + ch];
      }
      else if (i < OFF_U0)  v = gb2[i - OFF_GB2];
      else if (i < OFF_V0)  v = WU0[i - OFF_U0];
      else if (i < OFF_U1)  v = WV0[i - OFF_V0];
      else if (i < OFF_V1)  v = WU1[i - OFF_U1];
      else if (i < OFF_U2)  v = WV1[i - OFF_V1];
      else if (i < OFF_V2)  v = WU2[i - OFF_U2];
      else                  v = WV2[i - OFF_V2];
      sWb[i] = pack2(v.x, v.y);
    }
  }
  __syncthreads();

  if (act){
    const float4* row4 = (const float4*)(xsph + (size_t)atom * 480);
    float o0 = 0.f, o2 = 0.f, o6 = 0.f;
    float o1[5] = {0,0,0,0,0}, o4[5] = {0,0,0,0,0}, o5[5] = {0,0,0,0,0}, o8[5] = {0,0,0,0,0};
    float o3[3] = {0,0,0}, o7[3] = {0,0,0};

    for (int half = 0; half < 2; ++half){
      const int co = half * 4;   // u32 column offset into 8-u32 (16-ch) weight rows

      // w-slice for instruction k (8 channels of this half); pure v_dot2_f32_bf16
      auto calcw = [&](int k, float* wsl){
#pragma unroll
        for (int c = 0; c < 4; ++c){
          u32 b = sWb[OFF_GB2 + k*8 + co + c];
          wsl[2*c] = blo(b); wsl[2*c+1] = bhi(b);
        }
        const u32* wrow = &sWb[k*16 + co*2];   // channel base = k*16 + half*8
#pragma unroll 2
        for (int cp = 0; cp < 16; ++cp){
          uint2 hh = *(const uint2*)&sWh[cp*512 + tid*2]; // rows (4cp,4cp+1),(4cp+2,4cp+3)
          const u32* r0 = wrow + (2*cp)*144;
          const u32* r1 = r0 + 144;
#pragma unroll
          for (int c = 0; c < 8; ++c){
            float acc = wsl[c];
            dot2bf(acc, hh.x, r0[c]);
            dot2bf(acc, hh.y, r1[c]);
            wsl[c] = acc;
          }
        }
      };

      float wsl[8];

      // ---- l = 0 : U0, V0 (8 channels of this half) ----
      float aU0[8], aV0[8];
#pragma unroll
      for (int c = 0; c < 8; ++c){ aU0[c] = 0.f; aV0[c] = 0.f; }
      {
        float4 xv = row4[0];
#pragma unroll 1
        for (int k4 = 0; k4 < 32; ++k4){
          float4 xn = row4[(k4 + 1) & 31];
          float xe[4] = {xv.x, xv.y, xv.z, xv.w};
#pragma unroll
          for (int e = 0; e < 4; ++e){
            const u32* wu = &sWb[OFF_U0 + (4*k4 + e)*8 + co];
            const u32* wv = &sWb[OFF_V0 + (4*k4 + e)*8 + co];
            float x = xe[e];
#pragma unroll
            for (int c = 0; c < 4; ++c){
              u32 a = wu[c], b = wv[c];
              aU0[2*c]   += x*blo(a);
              aU0[2*c+1] += x*bhi(a);
              aV0[2*c]   += x*blo(b);
              aV0[2*c+1] += x*bhi(b);
            }
          }
          xv = xn;
        }
      }
#pragma unroll
      for (int c = 0; c < 8; ++c){ aU0[c] *= 0.08838834764831845f; aV0[c] *= 0.08838834764831845f; }

      calcw(0, wsl);                               // k0 (0,0,0)
#pragma unroll
      for (int u = 0; u < 8; ++u) o0 += aU0[u]*aV0[u]*wsl[u];

      // ---- l = 1 : U1, V1 (3 comps x 8 channels) ----
      {
        float aU1[24], aV1[24];
#pragma unroll
        for (int c = 0; c < 24; ++c){ aU1[c] = 0.f; aV1[c] = 0.f; }
        float4 fa = row4[32], fb = row4[33], fc = row4[34];
#pragma unroll 1
        for (int g4 = 0; g4 < 16; ++g4){
          int gn = (g4 + 1) & 15;
          float4 na = row4[32 + 3*gn], nb = row4[33 + 3*gn], nc = row4[34 + 3*gn];
          float f12[12] = {fa.x,fa.y,fa.z,fa.w, fb.x,fb.y,fb.z,fb.w, fc.x,fc.y,fc.z,fc.w};
#pragma unroll
          for (int s = 0; s < 4; ++s){
            int uu = 4*g4 + s;
            float x0 = f12[3*s], x1 = f12[3*s+1], x2 = f12[3*s+2];
            const u32* wu = &sWb[OFF_U1 + uu*8 + co];
            const u32* wv = &sWb[OFF_V1 + uu*8 + co];
#pragma unroll
            for (int c = 0; c < 4; ++c){
              u32 a = wu[c];
              float uA = blo(a), uAh = bhi(a);
              aU1[2*c]      += x0*uA;  aU1[2*c+1]    += x0*uAh;
              aU1[8+2*c]    += x1*uA;  aU1[8+2*c+1]  += x1*uAh;
              aU1[16+2*c]   += x2*uA;  aU1[16+2*c+1] += x2*uAh;
              u32 b = wv[c];
              float vA = blo(b), vAh = bhi(b);
              aV1[2*c]      += x0*vA;  aV1[2*c+1]    += x0*vAh;
              aV1[8+2*c]    += x1*vA;  aV1[8+2*c+1]  += x1*vAh;
              aV1[16+2*c]   += x2*vA;  aV1[16+2*c+1] += x2*vAh;
            }
          }
          fa = na; fb = nb; fc = nc;
        }
#pragma unroll
        for (int c = 0; c < 24; ++c){ aU1[c] *= 0.125f; aV1[c] *= 0.125f; }

        calcw(2, wsl);                             // k2 (1,1,0)
#pragma unroll
        for (int u = 0; u < 8; ++u)
          o2 += (aU1[u]*aV1[u] + aU1[8+u]*aV1[8+u] + aU1[16+u]*aV1[16+u]) * wsl[u];

        calcw(3, wsl);                             // k3 (1,1,1)
#pragma unroll
        for (int u = 0; u < 8; ++u){
          float a0 = aU1[u], a1 = aU1[8+u], a2 = aU1[16+u];
          float b0 = aV1[u], b1 = aV1[8+u], b2 = aV1[16+u];
          float wv = wsl[u];
          o3[0] += wv*(a1*b2 - a2*b1);
          o3[1] += wv*(a2*b0 - a0*b2);
          o3[2] += wv*(a0*b1 - a1*b0);
        }

        calcw(4, wsl);                             // k4 (1,1,2)
#pragma unroll
        for (int u = 0; u < 8; ++u){
          float wv = wsl[u];
          float a0 = aU1[u]*wv, a1 = aU1[8+u]*wv, a2 = aU1[16+u]*wv;
          float b0 = aV1[u], b1 = aV1[8+u], b2 = aV1[16+u];
          o4[0] += -0.17677669529663687f*(a0*b2 + a2*b0);
          o4[1] += -0.17677669529663687f*(a0*b1 + a1*b0);
          o4[2] +=  0.10206207261596577f*(a0*b0 + a2*b2) - 0.20412414523193154f*a1*b1;
          o4[3] += -0.17677669529663687f*(a2*b1 + a1*b2);
          o4[4] +=  0.17677669529663687f*(a0*b0 - a2*b2);
        }
      }

      // ---- l = 2 : U2, V2 (5 comps x 8 channels) ----
      {
        float aU2[40], aV2[40];
#pragma unroll
        for (int c = 0; c < 40; ++c){ aU2[c] = 0.f; aV2[c] = 0.f; }
        float4 qa = row4[80], qb = row4[81], qc = row4[82], qd = row4[83], qe = row4[84];
#pragma unroll 1
        for (int g4 = 0; g4 < 8; ++g4){
          int gn = (g4 + 1) & 7;
          float4 pa = row4[80+5*gn], pb = row4[81+5*gn], pc = row4[82+5*gn],
                 pd = row4[83+5*gn], pe = row4[84+5*gn];
          float f20[20] = {qa.x,qa.y,qa.z,qa.w, qb.x,qb.y,qb.z,qb.w, qc.x,qc.y,qc.z,qc.w,
                           qd.x,qd.y,qd.z,qd.w, qe.x,qe.y,qe.z,qe.w};
#pragma unroll
          for (int s = 0; s < 4; ++s){
            int uu = 4*g4 + s;
            const u32* wu = &sWb[OFF_U2 + uu*8 + co];
            const u32* wv = &sWb[OFF_V2 + uu*8 + co];
#pragma unroll
            for (int c = 0; c < 4; ++c){
              u32 a = wu[c];
              float uA = blo(a), uAh = bhi(a);
              u32 b = wv[c];
              float vA = blo(b), vAh = bhi(b);
#pragma unroll
              for (int m = 0; m < 5; ++m){
                float xm = f20[5*s + m];
                aU2[m*8+2*c]   += xm*uA;
                aU2[m*8+2*c+1] += xm*uAh;
                aV2[m*8+2*c]   += xm*vA;
                aV2[m*8+2*c+1] += xm*vAh;
              }
            }
          }
          qa=pa; qb=pb; qc=pc; qd=pd; qe=pe;
        }
#pragma unroll
        for (int c = 0; c < 40; ++c){ aU2[c] *= 0.17677669529663687f; aV2[c] *= 0.17677669529663687f; }

        calcw(1, wsl);                             // k1 (0,2,2)
#pragma unroll
        for (int u = 0; u < 8; ++u){
          float t = aU0[u]*wsl[u];
          o1[0] += t*aV2[u];      o1[1] += t*aV2[8+u];  o1[2] += t*aV2[16+u];
          o1[3] += t*aV2[24+u];   o1[4] += t*aV2[32+u];
        }

        calcw(5, wsl);                             // k5 (2,0,2)
#pragma unroll
        for (int u = 0; u < 8; ++u){
          float t = aV0[u]*wsl[u];
          o5[0] += aU2[u]*t;      o5[1] += aU2[8+u]*t;  o5[2] += aU2[16+u]*t;
          o5[3] += aU2[24+u]*t;   o5[4] += aU2[32+u]*t;
        }

        calcw(6, wsl);                             // k6 (2,2,0)
#pragma unroll
        for (int u = 0; u < 8; ++u)
          o6 += wsl[u]*(aU2[u]*aV2[u] + aU2[8+u]*aV2[8+u] + aU2[16+u]*aV2[16+u]
                      + aU2[24+u]*aV2[24+u] + aU2[32+u]*aV2[32+u]);

        calcw(7, wsl);                             // k7 (2,2,1)
#pragma unroll
        for (int u = 0; u < 8; ++u){
          float wv = wsl[u];
          float A0 = aU2[u], A1 = aU2[8+u], A2 = aU2[16+u], A3 = aU2[24+u], A4 = aU2[32+u];
          float B0 = aV2[u], B1 = aV2[8+u], B2 = aV2[16+u], B3 = aV2[24+u], B4 = aV2[32+u];
          o7[0] += wv*( 0.07905694150420949f*(A0*B1 - A1*B0)
                       -0.13693063937629153f*(A2*B3 - A3*B2)
                       -0.07905694150420949f*(A3*B4 - A4*B3));
          o7[1] += wv*( 0.15811388300841897f*(A0*B4 - A4*B0)
                       +0.07905694150420949f*(A1*B3 - A3*B1));
          o7[2] += wv*(-0.07905694150420949f*(A0*B3 - A3*B0)
                       -0.13693063937629153f*(A1*B2 - A2*B1)
                       -0.07905694150420949f*(A1*B4 - A4*B1));
        }

        calcw(8, wsl);                             // k8 (2,2,2)
#pragma unroll
        for (int u = 0; u < 8; ++u){
          float wv = wsl[u];
          float A0 = aU2[u]*wv, A1 = aU2[8+u]*wv, A2 = aU2[16+u]*wv, A3 = aU2[24+u]*wv, A4 = aU2[32+u]*wv;
          float B0 = aV2[u], B1 = aV2[8+u], B2 = aV2[16+u], B3 = aV2[24+u], B4 = aV2[32+u];
          o8[0] +=  0.13363062095621219f*(A0*B2 + A2*B0) - 0.11572751768169277f*(A1*B3 + A3*B1);
          o8[1] += -0.06681531047810609f*(A1*B2 + A2*B1) + 0.11572751768169277f*(A1*B4 + A4*B1)
                   -0.11572751768169277f*(A0*B3 + A3*B0);
          o8[2] +=  0.13363062095621219f*(A0*B0 + A4*B4) - 0.06681531047810609f*(A1*B1 + A3*B3)
                   -0.13363062095621219f*A2*B2;
          o8[3] += -0.11572751768169277f*(A0*B1 + A1*B0) - 0.06681531047810609f*(A2*B3 + A3*B2)
                   -0.11572751768169277f*(A3*B4 + A4*B3);
          o8[4] +=  0.13363062095621219f*(A2*B4 + A4*B2) + 0.11572751768169277f*(A1*B1 - A3*B3);
        }
      }
    } // half

    o0 *= 0.25f;
    o2 *= 0.14433756729740643f;
    o6 *= 0.11180339887498948f;

    float p00 = Wp0[0], p01 = Wp0[1], p02 = Wp0[2];
    float p10 = Wp1[0], p11 = Wp1[1];
    float p20 = Wp2[0], p21 = Wp2[1], p22 = Wp2[2], p23 = Wp2[3];
    float ao[9];
    ao[0] = (o0*p00 + o2*p01 + o6*p02) * 0.5773502691896258f;
#pragma unroll
    for (int i = 0; i < 3; ++i)
      ao[1+i] = (o3[i]*0.17677669529663687f*p10 + o7[i]*p11) * 0.7071067811865476f;
#pragma unroll
    for (int m = 0; m < 5; ++m)
      ao[4+m] = (o1[m]*0.25f*p20 + o4[m]*p21 + o5[m]*0.25f*p22 + o8[m]*p23) * 0.5f;

    int g = batch[atom];
    int off = g - gmin;
    if (off >= 0 && off < RED_WIN){
#pragma unroll
      for (int c = 0; c < 9; ++c) atomicAdd(&red[off*9 + c], ao[c]);
    } else {
#pragma unroll
      for (int c = 0; c < 9; ++c) atomicAdd(&accum[g*9 + c], ao[c]);
    }
  }
  __syncthreads();

  int range = gmax - gmin + 1; if (range > RED_WIN) range = RED_WIN;
  for (int i = tid; i < range*9; i += THREADS){
    float v = red[i];
    if (v != 0.f) atomicAdd(&accum[(gmin + i/9)*9 + (i%9)], v);
  }
}

// ---------------- final: res_sph @ Q, permute, write fp32 ----------------
__constant__ float Qc[81] = {
  0.5773502691896258f, 0.f, 0.f,  0.f, 0.5773502691896258f, 0.f,  0.f, 0.f, 0.5773502691896258f,
  0.f, 0.f, 0.f,  0.f, 0.f, 0.7071067811865476f,  0.f, -0.7071067811865476f, 0.f,
  0.f, 0.f, -0.7071067811865476f,  0.f, 0.f, 0.f,  0.7071067811865476f, 0.f, 0.f,
  0.f, 0.7071067811865476f, 0.f,  -0.7071067811865476f, 0.f, 0.f,  0.f, 0.f, 0.f,
  0.f, 0.f, -0.7071067811865476f,  0.f, 0.f, 0.f,  -0.7071067811865476f, 0.f, 0.f,
  0.f, -0.7071067811865476f, 0.f,  -0.7071067811865476f, 0.f, 0.f,  0.f, 0.f, 0.f,
  0.4082482904638631f, 0.f, 0.f,  0.f, -0.8164965809277260f, 0.f,  0.f, 0.f, 0.4082482904638631f,
  0.f, 0.f, 0.f,  0.f, 0.f, -0.7071067811865476f,  0.f, -0.7071067811865476f, 0.f,
  0.7071067811865476f, 0.f, 0.f,  0.f, 0.f, 0.f,  0.f, 0.f, -0.7071067811865476f
};

__global__ __launch_bounds__(THREADS) void final_kernel(
    const float* __restrict__ accum, float* __restrict__ out, int NG)
{
  int t = blockIdx.x * THREADS + threadIdx.x;
  if (t >= NG*9) return;
  int g = t / 9, r = t - 9*g, i = r / 3, j = r - 3*i;
  int a = (i == 0) ? 2 : (i == 1 ? 0 : 1);
  int b = (j == 0) ? 2 : (j == 1 ? 0 : 1);
  float s = 0.f;
#pragma unroll
  for (int rr = 0; rr < 9; ++rr) s += accum[g*9 + rr] * Qc[rr*9 + a*3 + b];
  out[t] = s;
}

// ---------------- launch ----------------
extern "C" void kernel_launch(void* const* d_in, const int* in_sizes, int n_in,
                              void* d_out, int out_size, void* d_ws, size_t ws_size,
                              hipStream_t stream)
{
  (void)n_in; (void)ws_size;
  const int NA = in_sizes[0];
  const int NG = out_size / 9;

  const int*    batch = (const int*)d_in[0];
  const float*  xs    = (const float*)d_in[1];
  const float*  xsph  = (const float*)d_in[2];
  const float2* WU0   = (const float2*)d_in[3];
  const float2* WU1   = (const float2*)d_in[4];
  const float2* WU2   = (const float2*)d_in[5];
  const float2* WV0   = (const float2*)d_in[6];
  const float2* WV1   = (const float2*)d_in[7];
  const float2* WV2   = (const float2*)d_in[8];
  const float2* gw1   = (const float2*)d_in[9];
  const float2* gb1   = (const float2*)d_in[10];
  const float2* gw2   = (const float2*)d_in[11];
  const float2* gb2   = (const float2*)d_in[12];
  const float*  Wp0   = (const float*)d_in[13];
  const float*  Wp1   = (const float*)d_in[14];
  const float*  Wp2   = (const float*)d_in[15];

  float* accum = (float*)d_ws;   // NG*9 fp32 = 36 KB

  int nb = (NA + THREADS - 1) / THREADS;
  hipMemsetAsync(accum, 0, (size_t)NG * 9 * sizeof(float), stream);
  fused_kernel<<<dim3(nb), dim3(THREADS), 0, stream>>>(
      batch, xs, xsph, WU0, WU1, WU2, WV0, WV1, WV2,
      gw1, gb1, gw2, gb2, Wp0, Wp1, Wp2, accum, NA);
  final_kernel<<<dim3((NG*9 + THREADS - 1)/THREADS), dim3(THREADS), 0, stream>>>(
      accum, (float*)d_out, NG);
}